// Round 17
// baseline (79.770 us; speedup 1.0000x reference)
//
#include <hip/hip_runtime.h>
#include <math.h>

#define IMG_H 512
#define IMG_W 512
#define TH 8                 // output rows per band
#define KR 5                 // radius
#define KS 11                // taps
#define NR (TH + 2 * KR)     // 18 input rows per band
#define LWE 524              // f32x4 elems per row: cols -6..517 at e=col+6
#define NTHREADS 512
#define NBANDS (IMG_H / TH)  // 64
#define NPLANES 48
#define NBLK (NBANDS * NPLANES)   // 3072, divisible by 8

typedef float f32x4 __attribute__((ext_vector_type(4)));

struct W22 { float w[2 * KS]; };   // w[2k] == w[2k+1] == gaussian tap k

// 16B-elem XOR swizzle (elem = one f32x4).
__device__ __forceinline__ int swz(int e) { return e ^ ((e >> 3) & 7); }

// Ablation template. MODE 1: global loads only (+sum). MODE 2: loads +
// vertical conv (+sum of accs). MODE 4: full R14 kernel (real output).
// All modes share phase-A code and keep the 67KB LDS allocated (identical
// occupancy context) so per-dispatch durations give true marginal costs.
template <int MODE>
__global__ __launch_bounds__(NTHREADS, 4)
void ssim_abl(const float* __restrict__ img1, const float* __restrict__ img2,
              float* __restrict__ outv, W22 wt) {
    __shared__ f32x4 sE[TH][LWE];   // 67,072 B in all modes
    __shared__ float redw[NTHREADS / 64];

    const int bid   = blockIdx.x;
    const int sbid  = (bid & 7) * (NBLK / 8) + (bid >> 3);
    const int plane = sbid >> 6;
    const int band  = sbid & (NBANDS - 1);

    const int r0 = band * TH - KR;
    const float* __restrict__ p1 = img1 + (size_t)plane * (IMG_H * IMG_W);
    const float* __restrict__ p2 = img2 + (size_t)plane * (IMG_H * IMG_W);
    const int tid = threadIdx.x;

    // ---- shared phase A: loads ----
    float av[NR], bv[NR];
    {
        const float* __restrict__ g1 = p1 + tid;
        const float* __restrict__ g2 = p2 + tid;
        if (r0 >= 0 && r0 + NR <= IMG_H) {
            #pragma unroll
            for (int j = 0; j < NR; ++j) {
                av[j] = g1[(r0 + j) * IMG_W];
                bv[j] = g2[(r0 + j) * IMG_W];
            }
        } else {
            #pragma unroll
            for (int j = 0; j < NR; ++j) {
                const int  rr  = r0 + j;
                const bool ok  = (rr >= 0) && (rr < IMG_H);
                const int  rrc = min(max(rr, 0), IMG_H - 1);
                const float a = g1[rrc * IMG_W];
                const float b = g2[rrc * IMG_W];
                av[j] = ok ? a : 0.f;
                bv[j] = ok ? b : 0.f;
            }
        }
    }

    float lsum = 0.f;

    if (MODE == 1) {
        // loads only: trivial consume keeps them live
        #pragma unroll
        for (int j = 0; j < NR; ++j) lsum += av[j] + bv[j];
        // keep LDS allocated without doing LDS work (never executes)
        if (tid == 1023) sE[0][0] = (f32x4){lsum, 0.f, 0.f, 0.f};
    } else {
        // ---- shared: vertical conv ----
        f32x4 acc[TH];
        #pragma unroll
        for (int r = 0; r < TH; ++r) acc[r] = (f32x4){0.f, 0.f, 0.f, 0.f};
        #pragma unroll
        for (int j = 0; j < NR; ++j) {
            const float a = av[j], b = bv[j];
            f32x4 pv; pv.x = a; pv.y = b;
            pv.z = fmaf(a, a, b * b); pv.w = a * b;
            #pragma unroll
            for (int r = 0; r < TH; ++r) {
                const int k = j - r;
                if (k >= 0 && k < KS) {
                    f32x4 wv; wv.x = wt.w[2*k]; wv.y = wt.w[2*k + 1];
                    wv.z = wt.w[2*k]; wv.w = wt.w[2*k + 1];
                    acc[r] = __builtin_elementwise_fma(wv, pv, acc[r]);
                }
            }
        }

        if (MODE == 2) {
            #pragma unroll
            for (int r = 0; r < TH; ++r)
                lsum += acc[r].x + acc[r].y + acc[r].z + acc[r].w;
            if (tid == 1023) sE[0][0] = (f32x4){lsum, 0.f, 0.f, 0.f};
        } else {
            // ---- full: stage + hconv + map ----
            if (tid < 128) {
                const int h = tid & 15;
                if (h < 12) {
                    const int r = tid >> 4;
                    const int e = (h < 6) ? h : (512 + h);
                    sE[r][swz(e)] = (f32x4){0.f, 0.f, 0.f, 0.f};
                }
            }
            {
                const int slot = swz(tid + 6);
                #pragma unroll
                for (int r = 0; r < TH; ++r) sE[r][slot] = acc[r];
            }
            __syncthreads();

            const float C1f = 0.0001f, C2f = 0.0009f;
            const int g  = tid >> 6;
            const int L  = tid & 63;
            const int eb = (L << 3) + 1;

            f32x4 x[18];
            #pragma unroll
            for (int i = 0; i < 18; ++i) x[i] = sE[g][swz(eb + i)];

            #pragma unroll
            for (int jj = 0; jj < 8; ++jj) {
                f32x4 c;
                {
                    f32x4 wv; wv.x = wt.w[0]; wv.y = wt.w[1];
                    wv.z = wt.w[0]; wv.w = wt.w[1];
                    c = wv * x[jj];
                }
                #pragma unroll
                for (int k = 1; k < KS; ++k) {
                    f32x4 wv; wv.x = wt.w[2*k]; wv.y = wt.w[2*k + 1];
                    wv.z = wt.w[2*k]; wv.w = wt.w[2*k + 1];
                    c = __builtin_elementwise_fma(wv, x[jj + k], c);
                }
                const float m1 = c.x, m2 = c.y;
                const float pp = c.z, ab = c.w;
                const float mu11 = m1 * m1;
                const float mu22 = m2 * m2;
                const float mu12 = m1 * m2;
                const float t     = mu11 + mu22;
                const float sigpp = pp - t;
                const float sig12 = ab - mu12;
                const float num = fmaf(2.f, mu12, C1f) * fmaf(2.f, sig12, C2f);
                const float den = (t + C1f) * (sigpp + C2f);
                lsum = fmaf(num, __builtin_amdgcn_rcpf(den), lsum);
            }
        }
    }

    // ---- reduce: wave shuffle, then per-wave partials ----
    #pragma unroll
    for (int off = 32; off > 0; off >>= 1) lsum += __shfl_down(lsum, off);
    if ((tid & 63) == 0) redw[tid >> 6] = lsum;
    __syncthreads();
    if (tid == 0) {
        float t = 0.f;
        #pragma unroll
        for (int w = 0; w < NTHREADS / 64; ++w) t += redw[w];
        outv[sbid] = t;
    }
}

// Final reduce in double.
__global__ __launch_bounds__(256)
void ssim_reduce_kernel(const float4* __restrict__ bsums, int n4,
                        float* __restrict__ out, double inv_count) {
    __shared__ double red[256];
    double acc = 0.0;
    for (int i = threadIdx.x; i < n4; i += 256) {
        const float4 v = bsums[i];
        acc += (double)v.x + (double)v.y + (double)v.z + (double)v.w;
    }
    red[threadIdx.x] = acc;
    __syncthreads();
    #pragma unroll
    for (int off = 128; off > 0; off >>= 1) {
        if (threadIdx.x < off) red[threadIdx.x] += red[threadIdx.x + off];
        __syncthreads();
    }
    if (threadIdx.x == 0) out[0] = (float)(red[0] * inv_count);
}

extern "C" void kernel_launch(void* const* d_in, const int* in_sizes, int n_in,
                              void* d_out, int out_size, void* d_ws, size_t ws_size,
                              hipStream_t stream) {
    const float* img1 = (const float*)d_in[0];
    const float* img2 = (const float*)d_in[1];
    float* out = (float*)d_out;
    float* ws  = (float*)d_ws;

    W22 wt;
    {
        double g[KS], sum = 0.0;
        for (int i = 0; i < KS; ++i) {
            const double x = (double)(i - KR);
            g[i] = exp(-(x * x) / (2.0 * 1.5 * 1.5));
            sum += g[i];
        }
        for (int i = 0; i < KS; ++i) {
            wt.w[2*i]     = (float)(g[i] / sum);
            wt.w[2*i + 1] = (float)(g[i] / sum);
        }
    }

    // Diagnostic probes (write to scratch; timed as separate dispatches):
    ssim_abl<1><<<dim3(NBLK), NTHREADS, 0, stream>>>(img1, img2, ws, wt);
    ssim_abl<2><<<dim3(NBLK), NTHREADS, 0, stream>>>(img1, img2, ws + NBLK, wt);
    // Real computation:
    ssim_abl<4><<<dim3(NBLK), NTHREADS, 0, stream>>>(img1, img2, ws + 2 * NBLK, wt);

    const double inv_count = 1.0 / ((double)NPLANES * IMG_H * IMG_W);
    ssim_reduce_kernel<<<1, 256, 0, stream>>>((const float4*)(ws + 2 * NBLK),
                                              NBLK / 4, out, inv_count);
}

// Round 18
// 47.172 us; speedup vs baseline: 1.6911x; 1.6911x over previous
//
#include <hip/hip_runtime.h>
#include <math.h>

#define IMG_H 512
#define IMG_W 512
#define TH 8                 // output rows per band (registers)
#define SR 4                 // staged rows per LDS pass
#define KR 5                 // radius
#define KS 11                // taps
#define NR (TH + 2 * KR)     // 18 input rows per band
#define LWE 524              // f32x4 elems per staged row (cols -6..517 at e=col+6)
#define NTHREADS 512
#define NBANDS (IMG_H / TH)  // 64
#define NPLANES 48
#define NBLK (NBANDS * NPLANES)   // 3072, divisible by 8

typedef float f32x4 __attribute__((ext_vector_type(4)));

struct W22 { float w[2 * KS]; };   // w[2k] == w[2k+1] == gaussian tap k

// 16B-elem XOR swizzle (elem = one f32x4): dense for stride-1 writes and
// stride-4 window reads (each bank quad serves 8 lanes = 128B = floor).
__device__ __forceinline__ int swz(int e) { return e ^ ((e >> 3) & 7); }

// Fused SSIM band kernel: one 512x8 full-width band per block, 512 threads.
// Register-lean schedule so 4 blocks/CU (32 waves) coexist with TH=8 economy:
//  - vconv STREAMED: load row j, FMA into accs, discard (live ~45 VGPR,
//    no av[]/bv[] arrays -> no R15-style spill)
//  - stage rows 0-3 -> hconv pass -> stage rows 4-7 -> hconv pass
//  - hconv tap-major with a sliding 5-elem window (live ~60 VGPR)
// LDS 33.5 KB -> 4 blocks/CU; __launch_bounds__(512,8) caps VGPR at 64.
__global__ __launch_bounds__(NTHREADS, 8)
void ssim_tile_kernel(const float* __restrict__ img1, const float* __restrict__ img2,
                      float* __restrict__ bsums, W22 wt) {
    __shared__ f32x4 sE[SR][LWE];   // 33,536 B
    __shared__ float redw[NTHREADS / 64];

    // XCD-aware bijective remap (NBLK % 8 == 0): each XCD sweeps 6 whole
    // planes in ascending band order -> band halos hit its own L2.
    const int bid   = blockIdx.x;
    const int sbid  = (bid & 7) * (NBLK / 8) + (bid >> 3);
    const int plane = sbid >> 6;              // sbid / NBANDS
    const int band  = sbid & (NBANDS - 1);

    const int r0 = band * TH - KR;
    const float* __restrict__ p1 = img1 + (size_t)plane * (IMG_H * IMG_W);
    const float* __restrict__ p2 = img2 + (size_t)plane * (IMG_H * IMG_W);
    const int tid = threadIdx.x;

    // Zero-fill the 12 alignment-halo elems (cols -6..-1, 512..517) once;
    // data writes cover swz(6..517) only -> halo slots persist across passes.
    if (tid < 64) {
        const int h = tid & 15;
        if (h < 12) {
            const int r = tid >> 4;                    // 0..3
            const int e = (h < 6) ? h : (512 + h);
            sE[r][swz(e)] = (f32x4){0.f, 0.f, 0.f, 0.f};
        }
    }

    // ---- Phase A: STREAMED vertical 11-tap conv, one column per thread ----
    f32x4 acc[TH];
    #pragma unroll
    for (int r = 0; r < TH; ++r) acc[r] = (f32x4){0.f, 0.f, 0.f, 0.f};

    {
        const float* __restrict__ g1 = p1 + tid;
        const float* __restrict__ g2 = p2 + tid;
        if (r0 >= 0 && r0 + NR <= IMG_H) {
            #pragma unroll
            for (int j = 0; j < NR; ++j) {
                const float a = g1[(r0 + j) * IMG_W];
                const float b = g2[(r0 + j) * IMG_W];
                f32x4 pv; pv.x = a; pv.y = b;
                pv.z = fmaf(a, a, b * b); pv.w = a * b;
                #pragma unroll
                for (int r = 0; r < TH; ++r) {
                    const int k = j - r;              // compile-time
                    if (k >= 0 && k < KS) {
                        f32x4 wv; wv.x = wt.w[2*k]; wv.y = wt.w[2*k + 1];
                        wv.z = wt.w[2*k]; wv.w = wt.w[2*k + 1];
                        acc[r] = __builtin_elementwise_fma(wv, pv, acc[r]);
                    }
                }
            }
        } else {
            #pragma unroll
            for (int j = 0; j < NR; ++j) {
                const int  rr  = r0 + j;
                const bool ok  = (rr >= 0) && (rr < IMG_H);   // block-uniform
                const int  rrc = min(max(rr, 0), IMG_H - 1);
                float a = g1[rrc * IMG_W];
                float b = g2[rrc * IMG_W];
                a = ok ? a : 0.f;
                b = ok ? b : 0.f;
                f32x4 pv; pv.x = a; pv.y = b;
                pv.z = fmaf(a, a, b * b); pv.w = a * b;
                #pragma unroll
                for (int r = 0; r < TH; ++r) {
                    const int k = j - r;
                    if (k >= 0 && k < KS) {
                        f32x4 wv; wv.x = wt.w[2*k]; wv.y = wt.w[2*k + 1];
                        wv.z = wt.w[2*k]; wv.w = wt.w[2*k + 1];
                        acc[r] = __builtin_elementwise_fma(wv, pv, acc[r]);
                    }
                }
            }
        }
    }

    const int slot = swz(tid + 6);
    const float C1f = 0.0001f;   // 0.01^2
    const float C2f = 0.0009f;   // 0.03^2
    const int g  = tid >> 7;             // staged row 0..3 (wave-uniform)
    const int L  = tid & 127;
    const int eb = (L << 2) + 1;         // cols 4L..4L+3 need elems eb..eb+13

    float lsum = 0.f;

    #pragma unroll
    for (int pass = 0; pass < 2; ++pass) {
        // ---- stage this pass's 4 rows (those accs die here) ----
        #pragma unroll
        for (int r = 0; r < SR; ++r) sE[r][slot] = acc[pass * SR + r];
        __syncthreads();

        // ---- Phase B: tap-major hconv with sliding window; 1 row x 4 cols ----
        f32x4 c0 = {0.f,0.f,0.f,0.f}, c1 = {0.f,0.f,0.f,0.f};
        f32x4 c2 = {0.f,0.f,0.f,0.f}, c3 = {0.f,0.f,0.f,0.f};
        {
            f32x4 x0 = sE[g][swz(eb + 0)];
            f32x4 x1 = sE[g][swz(eb + 1)];
            f32x4 x2 = sE[g][swz(eb + 2)];
            f32x4 x3 = sE[g][swz(eb + 3)];
            #pragma unroll
            for (int k = 0; k < KS; ++k) {
                f32x4 wv; wv.x = wt.w[2*k]; wv.y = wt.w[2*k + 1];
                wv.z = wt.w[2*k]; wv.w = wt.w[2*k + 1];
                c0 = __builtin_elementwise_fma(wv, x0, c0);
                c1 = __builtin_elementwise_fma(wv, x1, c1);
                c2 = __builtin_elementwise_fma(wv, x2, c2);
                c3 = __builtin_elementwise_fma(wv, x3, c3);
                if (k < KS - 1) {                     // slide window
                    x0 = x1; x1 = x2; x2 = x3;
                    x3 = sE[g][swz(eb + 4 + k)];
                }
            }
        }
        #pragma unroll
        for (int jj = 0; jj < 4; ++jj) {
            const f32x4 c = (jj == 0) ? c0 : (jj == 1) ? c1 : (jj == 2) ? c2 : c3;
            const float m1 = c.x, m2 = c.y;
            const float pp = c.z, ab = c.w;
            const float mu11 = m1 * m1;
            const float mu22 = m2 * m2;
            const float mu12 = m1 * m2;
            const float t     = mu11 + mu22;
            const float sigpp = pp - t;              // sigma1_sq + sigma2_sq
            const float sig12 = ab - mu12;
            const float num = fmaf(2.f, mu12, C1f) * fmaf(2.f, sig12, C2f);
            const float den = (t + C1f) * (sigpp + C2f);
            lsum = fmaf(num, __builtin_amdgcn_rcpf(den), lsum);
        }
        if (pass == 0) __syncthreads();   // pass-0 reads done before rewrite
    }

    // ---- reduce: wave shuffle, then per-wave partials ----
    #pragma unroll
    for (int off = 32; off > 0; off >>= 1) lsum += __shfl_down(lsum, off);
    if ((tid & 63) == 0) redw[tid >> 6] = lsum;
    __syncthreads();
    if (tid == 0) {
        float t = 0.f;
        #pragma unroll
        for (int w = 0; w < NTHREADS / 64; ++w) t += redw[w];
        bsums[sbid] = t;
    }
}

// Final reduce in double (fp32 sequential sum of the 1.26e7-magnitude total
// would exceed the 2.6e-4 threshold).
__global__ __launch_bounds__(256)
void ssim_reduce_kernel(const float4* __restrict__ bsums, int n4,
                        float* __restrict__ out, double inv_count) {
    __shared__ double red[256];
    double acc = 0.0;
    for (int i = threadIdx.x; i < n4; i += 256) {
        const float4 v = bsums[i];
        acc += (double)v.x + (double)v.y + (double)v.z + (double)v.w;
    }
    red[threadIdx.x] = acc;
    __syncthreads();
    #pragma unroll
    for (int off = 128; off > 0; off >>= 1) {
        if (threadIdx.x < off) red[threadIdx.x] += red[threadIdx.x + off];
        __syncthreads();
    }
    if (threadIdx.x == 0) out[0] = (float)(red[0] * inv_count);
}

extern "C" void kernel_launch(void* const* d_in, const int* in_sizes, int n_in,
                              void* d_out, int out_size, void* d_ws, size_t ws_size,
                              hipStream_t stream) {
    const float* img1 = (const float*)d_in[0];
    const float* img2 = (const float*)d_in[1];
    float* out = (float*)d_out;
    float* bsums = (float*)d_ws;

    // Gaussian weights, computed in double like the numpy reference, cast to
    // f32, duplicated per tap (ready-made 64-bit SGPR pairs for pk_fma).
    W22 wt;
    {
        double g[KS], sum = 0.0;
        for (int i = 0; i < KS; ++i) {
            const double x = (double)(i - KR);
            g[i] = exp(-(x * x) / (2.0 * 1.5 * 1.5));
            sum += g[i];
        }
        for (int i = 0; i < KS; ++i) {
            wt.w[2*i]     = (float)(g[i] / sum);
            wt.w[2*i + 1] = (float)(g[i] / sum);
        }
    }

    ssim_tile_kernel<<<dim3(NBLK), NTHREADS, 0, stream>>>(img1, img2, bsums, wt);

    const double inv_count = 1.0 / ((double)NPLANES * IMG_H * IMG_W);
    ssim_reduce_kernel<<<1, 256, 0, stream>>>((const float4*)bsums, NBLK / 4,
                                              out, inv_count);
}

// Round 19
// 40.467 us; speedup vs baseline: 1.9712x; 1.1657x over previous
//
#include <hip/hip_runtime.h>
#include <math.h>

#define IMG_H 512
#define IMG_W 512
#define TH 8                 // output rows per band
#define KR 5                 // radius
#define KS 11                // taps
#define NR (TH + 2 * KR)     // 18 input rows per band
#define LWE 524              // f32x4 elems per row: cols -6..517 at e=col+6
#define NTHREADS 512
#define NBANDS (IMG_H / TH)  // 64
#define NPLANES 48
#define NBLK (NBANDS * NPLANES)   // 3072, divisible by 8

typedef float f32x4 __attribute__((ext_vector_type(4)));

struct W11 { float w[KS]; };   // gaussian taps

// 16B-elem XOR swizzle (elem = one f32x4). Phase-B reads have lane stride 8
// elems -> XOR spreads 8-elem blocks across bank quads (dense); phase-A
// stride-1 writes stay dense. Never escapes an aligned 8-elem block.
__device__ __forceinline__ int swz(int e) { return e ^ ((e >> 3) & 7); }

// Fused SSIM band kernel: one 512x8 full-width band per block, 512 threads.
// == R14 (measured best, 40.7us) with ONE change: all 11 weight quads are
// hoisted into a register array built ONCE, so no per-FMA vector rebuilds.
// Occupancy is LDS-bound (67KB -> 2 blocks/CU), so the ~44 VGPRs spent on
// resident weights are free under the (512,4) 128-VGPR cap.
__global__ __launch_bounds__(NTHREADS, 4)
void ssim_tile_kernel(const float* __restrict__ img1, const float* __restrict__ img2,
                      float* __restrict__ bsums, W11 wt) {
    __shared__ f32x4 sE[TH][LWE];   // 67,072 B
    __shared__ float redw[NTHREADS / 64];

    // XCD-aware bijective remap (NBLK % 8 == 0): each XCD sweeps 6 whole
    // planes in ascending band order -> band halos hit its own L2.
    const int bid   = blockIdx.x;
    const int sbid  = (bid & 7) * (NBLK / 8) + (bid >> 3);
    const int plane = sbid >> 6;              // sbid / NBANDS
    const int band  = sbid & (NBANDS - 1);

    const int r0 = band * TH - KR;
    const float* __restrict__ p1 = img1 + (size_t)plane * (IMG_H * IMG_W);
    const float* __restrict__ p2 = img2 + (size_t)plane * (IMG_H * IMG_W);
    const int tid = threadIdx.x;

    // ---- Hoist weight quads ONCE (register-resident across both convs) ----
    f32x4 wq[KS];
    #pragma unroll
    for (int k = 0; k < KS; ++k) {
        const float w = wt.w[k];
        wq[k] = (f32x4){w, w, w, w};
    }

    // Zero-fill the 12 alignment-halo elems (cols -6..-1, 512..517) x 8 rows.
    if (tid < 128) {
        const int h = tid & 15;
        if (h < 12) {
            const int r = tid >> 4;                    // 0..7
            const int e = (h < 6) ? h : (512 + h);
            sE[r][swz(e)] = (f32x4){0.f, 0.f, 0.f, 0.f};
        }
    }

    // ---- Phase A: vertical 11-tap conv, one column per thread ----
    float av[NR], bv[NR];
    {
        const float* __restrict__ g1 = p1 + tid;
        const float* __restrict__ g2 = p2 + tid;
        if (r0 >= 0 && r0 + NR <= IMG_H) {
            #pragma unroll
            for (int j = 0; j < NR; ++j) {
                av[j] = g1[(r0 + j) * IMG_W];
                bv[j] = g2[(r0 + j) * IMG_W];
            }
        } else {
            #pragma unroll
            for (int j = 0; j < NR; ++j) {
                const int  rr  = r0 + j;
                const bool ok  = (rr >= 0) && (rr < IMG_H);   // block-uniform
                const int  rrc = min(max(rr, 0), IMG_H - 1);
                const float a = g1[rrc * IMG_W];
                const float b = g2[rrc * IMG_W];
                av[j] = ok ? a : 0.f;
                bv[j] = ok ? b : 0.f;
            }
        }
    }

    f32x4 acc[TH];
    #pragma unroll
    for (int r = 0; r < TH; ++r) acc[r] = (f32x4){0.f, 0.f, 0.f, 0.f};

    #pragma unroll
    for (int j = 0; j < NR; ++j) {
        const float a = av[j], b = bv[j];
        f32x4 pv; pv.x = a; pv.y = b;
        pv.z = fmaf(a, a, b * b); pv.w = a * b;
        #pragma unroll
        for (int r = 0; r < TH; ++r) {
            const int k = j - r;                      // compile-time
            if (k >= 0 && k < KS)
                acc[r] = __builtin_elementwise_fma(wq[k], pv, acc[r]);
        }
    }
    {
        const int slot = swz(tid + 6);
        #pragma unroll
        for (int r = 0; r < TH; ++r) sE[r][slot] = acc[r];
    }
    __syncthreads();

    // ---- Phase B: horizontal conv + SSIM map; 1 row x 8 consecutive cols ----
    const float C1f = 0.0001f;   // 0.01^2
    const float C2f = 0.0009f;   // 0.03^2
    const int g  = tid >> 6;             // 8 rows x 64 lanes
    const int L  = tid & 63;
    const int eb = (L << 3) + 1;         // cols 8L..8L+7 need elems eb..eb+17

    f32x4 x[18];
    #pragma unroll
    for (int i = 0; i < 18; ++i) x[i] = sE[g][swz(eb + i)];

    float lsum = 0.f;
    #pragma unroll
    for (int jj = 0; jj < 8; ++jj) {
        f32x4 c = wq[0] * x[jj];
        #pragma unroll
        for (int k = 1; k < KS; ++k)
            c = __builtin_elementwise_fma(wq[k], x[jj + k], c);
        const float m1 = c.x, m2 = c.y;
        const float pp = c.z, ab = c.w;
        const float mu11 = m1 * m1;
        const float mu22 = m2 * m2;
        const float mu12 = m1 * m2;
        const float t     = mu11 + mu22;
        const float sigpp = pp - t;              // sigma1_sq + sigma2_sq
        const float sig12 = ab - mu12;
        const float num = fmaf(2.f, mu12, C1f) * fmaf(2.f, sig12, C2f);
        const float den = (t + C1f) * (sigpp + C2f);
        lsum = fmaf(num, __builtin_amdgcn_rcpf(den), lsum);
    }

    // ---- reduce: wave shuffle, then per-wave partials ----
    #pragma unroll
    for (int off = 32; off > 0; off >>= 1) lsum += __shfl_down(lsum, off);
    if ((tid & 63) == 0) redw[tid >> 6] = lsum;
    __syncthreads();
    if (tid == 0) {
        float t = 0.f;
        #pragma unroll
        for (int w = 0; w < NTHREADS / 64; ++w) t += redw[w];
        bsums[sbid] = t;
    }
}

// Final reduce in double (fp32 sequential sum of the 1.26e7-magnitude total
// would exceed the 2.6e-4 threshold).
__global__ __launch_bounds__(256)
void ssim_reduce_kernel(const float4* __restrict__ bsums, int n4,
                        float* __restrict__ out, double inv_count) {
    __shared__ double red[256];
    double acc = 0.0;
    for (int i = threadIdx.x; i < n4; i += 256) {
        const float4 v = bsums[i];
        acc += (double)v.x + (double)v.y + (double)v.z + (double)v.w;
    }
    red[threadIdx.x] = acc;
    __syncthreads();
    #pragma unroll
    for (int off = 128; off > 0; off >>= 1) {
        if (threadIdx.x < off) red[threadIdx.x] += red[threadIdx.x + off];
        __syncthreads();
    }
    if (threadIdx.x == 0) out[0] = (float)(red[0] * inv_count);
}

extern "C" void kernel_launch(void* const* d_in, const int* in_sizes, int n_in,
                              void* d_out, int out_size, void* d_ws, size_t ws_size,
                              hipStream_t stream) {
    const float* img1 = (const float*)d_in[0];
    const float* img2 = (const float*)d_in[1];
    float* out = (float*)d_out;
    float* bsums = (float*)d_ws;

    // Gaussian weights, computed in double like the numpy reference.
    W11 wt;
    {
        double g[KS], sum = 0.0;
        for (int i = 0; i < KS; ++i) {
            const double x = (double)(i - KR);
            g[i] = exp(-(x * x) / (2.0 * 1.5 * 1.5));
            sum += g[i];
        }
        for (int i = 0; i < KS; ++i) wt.w[i] = (float)(g[i] / sum);
    }

    ssim_tile_kernel<<<dim3(NBLK), NTHREADS, 0, stream>>>(img1, img2, bsums, wt);

    const double inv_count = 1.0 / ((double)NPLANES * IMG_H * IMG_W);
    ssim_reduce_kernel<<<1, 256, 0, stream>>>((const float4*)bsums, NBLK / 4,
                                              out, inv_count);
}